// Round 3
// baseline (338.026 us; speedup 1.0000x reference)
//
#include <hip/hip_runtime.h>
#include <hip/hip_bf16.h>

typedef unsigned short USHORT;
typedef long long LL;

// B=2, L=256, H=512, NH=8, DH=64, MAXLEN=256, PE_ROWS=513

__device__ __forceinline__ float bf2f(USHORT u) {
  union { unsigned int i; float f; } v; v.i = ((unsigned int)u) << 16; return v.f;
}
__device__ __forceinline__ USHORT f2bf(float f) {
  unsigned int x = __float_as_uint(f);
  unsigned int r = (x + 0x7fffu + ((x >> 16) & 1u)) >> 16;
  return (USHORT)r;
}

// flags[0]=1 iff float inputs are bf16; flags[1]=1 iff int inputs are int64
__global__ void detect_k(const USHORT* __restrict__ q, const int* __restrict__ sl,
                         int* __restrict__ flags) {
  if (threadIdx.x == 0 && blockIdx.x == 0) {
    int wild = 0;
    for (int i = 0; i < 512; i++) {
      float x = bf2f(q[i]);
      if (!(fabsf(x) <= 1024.0f)) wild++;  // catches NaN too
    }
    flags[0] = (wild == 0) ? 1 : 0;
    flags[1] = (sl[1] == 0) ? 1 : 0;
  }
}

struct CvtF { const void* src[18]; float* dst[18]; int n[18]; };

__global__ __launch_bounds__(256) void cvt_f_k(CvtF a, const int* __restrict__ flags) {
  const int f = flags[0];
  const int idx = blockIdx.y;
  const int n = a.n[idx];
  const USHORT* sb = (const USHORT*)a.src[idx];
  const float* sf = (const float*)a.src[idx];
  float* d = a.dst[idx];
  for (int i = blockIdx.x * blockDim.x + threadIdx.x; i < n; i += gridDim.x * blockDim.x)
    d[i] = f ? bf2f(sb[i]) : sf[i];
}

__global__ __launch_bounds__(256) void cvt_i_k(
    const void* s0, const void* s1, const void* s2, const void* s3,
    int* d0, int* d1, int* d2, int* d3, const int* __restrict__ flags) {
  const int f = flags[1];
  const int t = threadIdx.x;
  if (t < 2) {
    d0[t] = f ? (int)((const LL*)s0)[t] : ((const int*)s0)[t];
    d1[t] = f ? (int)((const LL*)s1)[t] : ((const int*)s1)[t];
  }
  for (int i = t; i < 512; i += 256) {
    d2[i] = f ? (int)((const LL*)s2)[i] : ((const int*)s2)[i];
    d3[i] = f ? (int)((const LL*)s3)[i] : ((const int*)s3)[i];
  }
}

// C = A @ W^T (+bias). A: [M,K] f32. W: [N, ldw] f32 (+ z*wz k-offset).
// out_flagged: store bf16 iff flags[0] else f32 (no z). Else f32 with z*out_zstride.
__global__ __launch_bounds__(256) void gemm_k(
    const float* __restrict__ A0, const float* __restrict__ A1,
    const float* __restrict__ A2, const float* __restrict__ A3, int lda,
    const float* __restrict__ W0, const float* __restrict__ W1,
    const float* __restrict__ W2, const float* __restrict__ W3, int ldw, int wz,
    const float* __restrict__ b0, const float* __restrict__ b1,
    const float* __restrict__ b2, const float* __restrict__ b3,
    void* __restrict__ Out, long out_zstride, int out_flagged,
    const int* __restrict__ flags, int M, int N, int K)
{
  __shared__ float As[64 * 20];
  __shared__ float Bs[64 * 20];
  const int z = blockIdx.z;
  const float* Ap = A0; const float* Wp = W0; const float* bp = b0;
  if (z == 1) { Ap = A1; Wp = W1; bp = b1; }
  else if (z == 2) { Ap = A2; Wp = W2; bp = b2; }
  else if (z == 3) { Ap = A3; Wp = W3; bp = b3; }
  Wp += (long)z * wz;

  const int t = threadIdx.x;
  const int row0 = blockIdx.y * 64, col0 = blockIdx.x * 64;
  const int lr = t >> 2, lk = (t & 3) * 4;
  const int tm = t >> 4, tn = t & 15;
  float acc[4][4] = {};

  for (int k0 = 0; k0 < K; k0 += 16) {
    float4 av;
    const int arow = row0 + lr;
    if (arow < M) av = *(const float4*)(Ap + (long)arow * lda + k0 + lk);
    else { av.x = av.y = av.z = av.w = 0.f; }
    float4 wv = *(const float4*)(Wp + (long)(col0 + lr) * ldw + k0 + lk);
    __syncthreads();
    *(float4*)&As[lr * 20 + lk] = av;
    *(float4*)&Bs[lr * 20 + lk] = wv;
    __syncthreads();
#pragma unroll
    for (int k4 = 0; k4 < 4; k4++) {
      float4 a[4], b[4];
#pragma unroll
      for (int mi = 0; mi < 4; mi++) a[mi] = *(const float4*)&As[(tm + 16 * mi) * 20 + k4 * 4];
#pragma unroll
      for (int ni = 0; ni < 4; ni++) b[ni] = *(const float4*)&Bs[(tn + 16 * ni) * 20 + k4 * 4];
#pragma unroll
      for (int mi = 0; mi < 4; mi++)
#pragma unroll
        for (int ni = 0; ni < 4; ni++)
          acc[mi][ni] += a[mi].x * b[ni].x + a[mi].y * b[ni].y + a[mi].z * b[ni].z + a[mi].w * b[ni].w;
    }
  }
  const int obf = out_flagged ? flags[0] : 0;
#pragma unroll
  for (int mi = 0; mi < 4; mi++) {
    const int r = row0 + tm + 16 * mi;
    if (r >= M) continue;
#pragma unroll
    for (int ni = 0; ni < 4; ni++) {
      const int c = col0 + tn + 16 * ni;
      float vo = acc[mi][ni];
      if (bp) vo += bp[c];
      const long off = (long)r * N + c;
      if (out_flagged) {
        if (obf) ((USHORT*)Out)[off] = f2bf(vo);
        else     ((float*)Out)[off] = vo;
      } else {
        ((float*)Out)[(long)z * out_zstride + off] = vo;
      }
    }
  }
}

// w[b,h,i,e] = sum_d (qp[b,i,h*64+d] + v[h,d]) * Wr[h*64+d, e]
__global__ __launch_bounds__(256) void wproj_k(
    const float* __restrict__ qp, const float* __restrict__ vf,
    const float* __restrict__ Wr, float* __restrict__ wout)
{
  __shared__ float As[64 * 68];  // [i][d]
  __shared__ float Bs[64 * 68];  // [e][d]
  const int t = threadIdx.x;
  const int b = blockIdx.z >> 3, h = blockIdx.z & 7;
  const int i0 = blockIdx.y * 64, e0 = blockIdx.x * 64;
  {
    const int i = t >> 2, db = (t & 3) * 4;
    const float* qrow = qp + (long)(b * 256 + i0 + i) * 512 + h * 64;
#pragma unroll
    for (int dd = 0; dd < 4; dd++) {
      const int d = db + 16 * dd;
      float4 q4 = *(const float4*)(qrow + d);
      float4 v4 = *(const float4*)(vf + h * 64 + d);
      float4 s;
      s.x = q4.x + v4.x; s.y = q4.y + v4.y; s.z = q4.z + v4.z; s.w = q4.w + v4.w;
      *(float4*)&As[i * 68 + d] = s;
    }
  }
  {
    const int d = t >> 2, eb = (t & 3) * 4;
    const float* wrow = Wr + (long)(h * 64 + d) * 512 + e0;
#pragma unroll
    for (int ee = 0; ee < 4; ee++) {
      const int e = eb + 16 * ee;
      float4 w4 = *(const float4*)(wrow + e);
      Bs[(e + 0) * 68 + d] = w4.x;
      Bs[(e + 1) * 68 + d] = w4.y;
      Bs[(e + 2) * 68 + d] = w4.z;
      Bs[(e + 3) * 68 + d] = w4.w;
    }
  }
  __syncthreads();
  const int tm = t >> 4, tn = t & 15;
  float acc[4][4] = {};
#pragma unroll
  for (int k4 = 0; k4 < 16; k4++) {
    float4 a[4], bb[4];
#pragma unroll
    for (int mi = 0; mi < 4; mi++) a[mi] = *(const float4*)&As[(tm + 16 * mi) * 68 + k4 * 4];
#pragma unroll
    for (int ni = 0; ni < 4; ni++) bb[ni] = *(const float4*)&Bs[(tn + 16 * ni) * 68 + k4 * 4];
#pragma unroll
    for (int mi = 0; mi < 4; mi++)
#pragma unroll
      for (int ni = 0; ni < 4; ni++)
        acc[mi][ni] += a[mi].x * bb[ni].x + a[mi].y * bb[ni].y + a[mi].z * bb[ni].z + a[mi].w * bb[ni].w;
  }
#pragma unroll
  for (int mi = 0; mi < 4; mi++)
#pragma unroll
    for (int ni = 0; ni < 4; ni++)
      wout[(long)((b * 8 + h) * 256 + i0 + tm + 16 * mi) * 512 + e0 + tn + 16 * ni] = acc[mi][ni];
}

// One block per (b,i). Builds relu tiles from P tables, scores, softmax, attn @ V.
__global__ __launch_bounds__(256) void score_k(
    const float* __restrict__ Ptab, const float* __restrict__ qp,
    const float* __restrict__ kp, const float* __restrict__ vp,
    const float* __restrict__ wbuf,
    const float* __restrict__ u_f, const float* __restrict__ v_f,
    const float* __restrict__ bf_f, const float* __restrict__ br_f,
    const int* __restrict__ seq_len, const int* __restrict__ lex_num,
    const int* __restrict__ pos_s, const int* __restrict__ pos_e,
    float* __restrict__ out_pre)
{
  __shared__ float relu_t[16 * 516];
  __shared__ float w_s[8 * 516];
  __shared__ float Sm[8 * 256];
  __shared__ float qu[8 * 68];
  __shared__ float bfv[512];
  __shared__ float part[128];
  __shared__ float red4[4];
  __shared__ float cbv[8];
  __shared__ int jidx[64];

  const int i = blockIdx.x;
  const int b = blockIdx.y;
  const int t = threadIdx.x;
  int tl = seq_len[b] + lex_num[b];
  tl = min(max(tl, 1), 256);
  const int psi = pos_s[b * 256 + i];
  const int pei = pos_e[b * 256 + i];
  const long qrow_off = (long)(b * 256 + i) * 512;

  {
    const int h = t >> 5, eb = (t & 31) * 16;
    const float* src = wbuf + (long)((b * 8 + h) * 256 + i) * 512 + eb;
#pragma unroll
    for (int m = 0; m < 4; m++)
      *(float4*)&w_s[h * 516 + eb + 4 * m] = *(const float4*)(src + 4 * m);
  }
  for (int c = t; c < 512; c += 256) {
    const int h = c >> 6, d = c & 63;
    qu[h * 68 + d] = qp[qrow_off + c] + u_f[c];
    bfv[c] = bf_f[c];
  }
  if (t < 8) {
    float s = 0.f;
    for (int d = 0; d < 64; d++) {
      const int c = t * 64 + d;
      s += (qp[qrow_off + c] + v_f[c]) * br_f[c];
    }
    cbv[t] = s;
  }
  __syncthreads();

  const float* P1 = Ptab;
  const float* P2 = Ptab + 513l * 512;
  const float* P3 = Ptab + 2l * 513 * 512;
  const float* P4 = Ptab + 3l * 513 * 512;

  const int ntiles = (tl + 15) >> 4;
  for (int jt = 0; jt < ntiles; jt++) {
    const int j0 = jt * 16;
    if (t < 16) {
      const int j = j0 + t;
      const int psj = pos_s[b * 256 + j];
      const int pej = pos_e[b * 256 + j];
      jidx[0 * 16 + t] = min(max(psi - psj + 256, 0), 512);
      jidx[1 * 16 + t] = min(max(psi - pej + 256, 0), 512);
      jidx[2 * 16 + t] = min(max(pei - psj + 256, 0), 512);
      jidx[3 * 16 + t] = min(max(pei - pej + 256, 0), 512);
    }
    __syncthreads();
    {
      const int e4 = (t & 127) * 4;
      const int jh = t >> 7;
#pragma unroll
      for (int jj2 = 0; jj2 < 8; jj2++) {
        const int jl = jh * 8 + jj2;
        float4 s0 = *(const float4*)(P1 + (long)jidx[0 * 16 + jl] * 512 + e4);
        float4 s1 = *(const float4*)(P2 + (long)jidx[1 * 16 + jl] * 512 + e4);
        float4 s2 = *(const float4*)(P3 + (long)jidx[2 * 16 + jl] * 512 + e4);
        float4 s3 = *(const float4*)(P4 + (long)jidx[3 * 16 + jl] * 512 + e4);
        float4 bb = *(const float4*)&bfv[e4];
        float4 r;
        r.x = fmaxf(s0.x + s1.x + s2.x + s3.x + bb.x, 0.f);
        r.y = fmaxf(s0.y + s1.y + s2.y + s3.y + bb.y, 0.f);
        r.z = fmaxf(s0.z + s1.z + s2.z + s3.z + bb.z, 0.f);
        r.w = fmaxf(s0.w + s1.w + s2.w + s3.w + bb.w, 0.f);
        *(float4*)&relu_t[jl * 516 + e4] = r;
      }
    }
    __syncthreads();
    {
      const int pid = t & 127;
      const int h = pid & 7;
      const int jj = pid >> 3;
      const int half = t >> 7;
      const int j = j0 + jj;
      float acc = 0.f;
      if (half == 0) {
        acc = cbv[h];
        const float* krow = kp + (long)(b * 256 + j) * 512 + h * 64;
#pragma unroll
        for (int d4 = 0; d4 < 64; d4 += 4) {
          float4 k4 = *(const float4*)(krow + d4);
          float4 q4 = *(const float4*)&qu[h * 68 + d4];
          acc += k4.x * q4.x + k4.y * q4.y + k4.z * q4.z + k4.w * q4.w;
        }
      }
      const int ebase = half * 256;
#pragma unroll 8
      for (int e4 = 0; e4 < 256; e4 += 4) {
        float4 r4 = *(const float4*)&relu_t[jj * 516 + ebase + e4];
        float4 w4 = *(const float4*)&w_s[h * 516 + ebase + e4];
        acc += r4.x * w4.x + r4.y * w4.y + r4.z * w4.z + r4.w * w4.w;
      }
      if (half) part[pid] = acc;
      __syncthreads();
      if (!half) Sm[h * 256 + j] = (acc + part[pid]) * 0.125f;
    }
    __syncthreads();
  }

  const int lane = t & 63, wid = t >> 6;
  for (int h = 0; h < 8; h++) {
    const float val = (t < tl) ? Sm[h * 256 + t] : -3.0e38f;
    float m = val;
#pragma unroll
    for (int off = 32; off > 0; off >>= 1) m = fmaxf(m, __shfl_xor(m, off));
    if (lane == 0) red4[wid] = m;
    __syncthreads();
    m = fmaxf(fmaxf(red4[0], red4[1]), fmaxf(red4[2], red4[3]));
    const float p = (t < tl) ? __expf(val - m) : 0.f;
    float s = p;
#pragma unroll
    for (int off = 32; off > 0; off >>= 1) s += __shfl_xor(s, off);
    __syncthreads();
    if (lane == 0) red4[wid] = s;
    __syncthreads();
    s = red4[0] + red4[1] + red4[2] + red4[3];
    if (!(s > 1e-30f)) s = 1.f;
    Sm[h * 256 + t] = p / s;
    __syncthreads();
  }

#pragma unroll
  for (int pass = 0; pass < 2; pass++) {
    const int h = (t >> 6) + 4 * pass;
    const int d = t & 63;
    const float* vcol = vp + (long)(b * 256) * 512 + h * 64 + d;
    float acc = 0.f;
#pragma unroll 4
    for (int j = 0; j < tl; j++) acc += Sm[h * 256 + j] * vcol[(long)j * 512];
    out_pre[qrow_off + h * 64 + d] = acc;
  }
}

extern "C" void kernel_launch(void* const* d_in, const int* in_sizes, int n_in,
                              void* d_out, int out_size, void* d_ws, size_t ws_size,
                              hipStream_t stream) {
  (void)in_sizes; (void)n_in; (void)out_size; (void)ws_size;

  float* ws = (float*)d_ws;
  int* flags = (int*)ws;                 // 4 ints
  float* p = ws + 4;
  float* c_key   = p; p += 262144;
  float* c_query = p; p += 262144;
  float* c_value = p; p += 262144;
  float* c_pe    = p; p += 262656;       // 513*512
  float* c_Wf    = p; p += 1048576;
  float* c_bf    = p; p += 512;
  float* c_Wk    = p; p += 262144;
  float* c_bk    = p; p += 512;
  float* c_Wq    = p; p += 262144;
  float* c_bq    = p; p += 512;
  float* c_Wv    = p; p += 262144;
  float* c_bv    = p; p += 512;
  float* c_Wr    = p; p += 262144;
  float* c_br    = p; p += 512;
  float* c_Wo    = p; p += 262144;
  float* c_bo    = p; p += 512;
  float* c_u     = p; p += 512;
  float* c_v     = p; p += 512;
  int* c_seq   = (int*)p; p += 4;
  int* c_lex   = (int*)p; p += 4;
  int* c_pos_s = (int*)p; p += 512;
  int* c_pos_e = (int*)p; p += 512;
  float* Ptab    = p; p += 1050624;      // 4*513*512
  float* qp      = p; p += 262144;
  float* kp      = p; p += 262144;
  float* vp      = p; p += 262144;
  float* wbuf    = p; p += 2097152;
  float* out_pre = p; p += 262144;

  detect_k<<<1, 64, 0, stream>>>((const USHORT*)d_in[1], (const int*)d_in[18], flags);

  CvtF ca;
  float* dsts[18] = {c_key, c_query, c_value, c_pe, c_Wf, c_bf, c_Wk, c_bk, c_Wq,
                     c_bq, c_Wv, c_bv, c_Wr, c_br, c_Wo, c_bo, c_u, c_v};
  int ns[18] = {262144, 262144, 262144, 262656, 1048576, 512, 262144, 512, 262144,
                512, 262144, 512, 262144, 512, 262144, 512, 512, 512};
  for (int i = 0; i < 18; i++) { ca.src[i] = d_in[i]; ca.dst[i] = dsts[i]; ca.n[i] = ns[i]; }
  cvt_f_k<<<dim3(256, 18), 256, 0, stream>>>(ca, flags);
  cvt_i_k<<<1, 256, 0, stream>>>(d_in[18], d_in[19], d_in[20], d_in[21],
                                 c_seq, c_lex, c_pos_s, c_pos_e, flags);

  dim3 blk(256, 1, 1);
  // P tables: P_t = pe @ Wf[:, t*512:(t+1)*512].T   (M=513, z=4)
  gemm_k<<<dim3(8, 9, 4), blk, 0, stream>>>(
      c_pe, c_pe, c_pe, c_pe, 512,
      c_Wf, c_Wf, c_Wf, c_Wf, 2048, 512,
      nullptr, nullptr, nullptr, nullptr,
      Ptab, 513l * 512, 0, flags, 513, 512, 512);
  // q/k/v projections
  gemm_k<<<dim3(8, 8, 3), blk, 0, stream>>>(
      c_query, c_key, c_value, c_value, 512,
      c_Wq, c_Wk, c_Wv, c_Wv, 512, 0,
      c_bq, c_bk, c_bv, c_bv,
      qp, 262144, 0, flags, 512, 512, 512);
  // w = (q_head + v) @ Wr_head
  wproj_k<<<dim3(8, 4, 16), blk, 0, stream>>>(qp, c_v, c_Wr, wbuf);
  // scores + softmax + attn@V
  score_k<<<dim3(256, 2), blk, 0, stream>>>(
      Ptab, qp, kp, vp, wbuf, c_u, c_v, c_bf, c_br,
      c_seq, c_lex, c_pos_s, c_pos_e, out_pre);
  // final: out = out_pre @ Wo.T + bo -> d_out (dtype per flags[0])
  gemm_k<<<dim3(8, 8, 1), blk, 0, stream>>>(
      out_pre, out_pre, out_pre, out_pre, 512,
      c_Wo, c_Wo, c_Wo, c_Wo, 512, 0,
      c_bo, c_bo, c_bo, c_bo,
      d_out, 0, 1, flags, 512, 512, 512);
}

// Round 5
// 283.811 us; speedup vs baseline: 1.1910x; 1.1910x over previous
//
#include <hip/hip_runtime.h>
#include <hip/hip_bf16.h>

typedef unsigned short USHORT;
typedef long long LL;
typedef short s8v __attribute__((ext_vector_type(8)));
typedef float f32x4 __attribute__((ext_vector_type(4)));

// B=2, L=256, H=512, NH=8, DH=64, MAXLEN=256, PE_ROWS=513
// Float inputs may be f32 OR bf16 -> runtime detect, canonicalize to bf16 (evidence:
// rounds 1/2/4 assumed bf16 -> NaN; round 3 dual-path -> pass => likely f32).
// Ints may be int32 or int64 -> runtime detect.

__device__ __forceinline__ float bf2f(USHORT u) {
  union { unsigned int i; float f; } v; v.i = ((unsigned int)u) << 16; return v.f;
}
__device__ __forceinline__ USHORT f2bf(float f) {
  unsigned int x = __float_as_uint(f);
  unsigned int r = (x + 0x7fffu + ((x >> 16) & 1u)) >> 16;
  return (USHORT)r;
}

// flags[0]=1 iff float inputs are bf16; flags[1] unused by others (int detect is inline)
__global__ void detect_k(const USHORT* __restrict__ q, int* __restrict__ flags) {
  if (threadIdx.x == 0 && blockIdx.x == 0) {
    int wild = 0;
    for (int i = 0; i < 512; i++) {
      float x = bf2f(q[i]);
      if (!(fabsf(x) <= 1024.0f)) wild++;  // catches NaN too
    }
    flags[0] = (wild == 0) ? 1 : 0;
  }
}

// int convert with embedded int64/int32 detection (seq_len[0] in [100,200) -> high word 0 iff i64)
__global__ void cvt_i_k(const void* s0, const void* s1, const void* s2, const void* s3,
                        int* d0, int* d1, int* d2, int* d3) {
  const int f = (((const int*)s0)[1] == 0) ? 1 : 0;
  const int t = threadIdx.x;
  if (t < 2) {
    d0[t] = f ? (int)((const LL*)s0)[t] : ((const int*)s0)[t];
    d1[t] = f ? (int)((const LL*)s1)[t] : ((const int*)s1)[t];
  }
  for (int i = t; i < 512; i += 256) {
    d2[i] = f ? (int)((const LL*)s2)[i] : ((const int*)s2)[i];
    d3[i] = f ? (int)((const LL*)s3)[i] : ((const int*)s3)[i];
  }
}

struct CvtF { const void* src[18]; USHORT* dst[18]; int n[18]; };

// canonical bf16 from either bf16 or f32 source
__global__ __launch_bounds__(256) void cvt_f_k(CvtF a, const int* __restrict__ flags) {
  const int f = flags[0];
  const int idx = blockIdx.y;
  const int n = a.n[idx];
  const USHORT* sb = (const USHORT*)a.src[idx];
  const float* sf = (const float*)a.src[idx];
  USHORT* d = a.dst[idx];
  for (int i = blockIdx.x * blockDim.x + threadIdx.x; i < n; i += gridDim.x * blockDim.x)
    d[i] = f ? sb[i] : f2bf(sf[i]);
}

// WrT[e][d] = Wr[d][e], 512x512 bf16 (canonical input)
__global__ __launch_bounds__(256) void transp_k(const USHORT* __restrict__ in,
                                                USHORT* __restrict__ out) {
  const int idx = blockIdx.x * 256 + threadIdx.x;
  const int e = idx >> 9, d = idx & 511;
  out[idx] = in[d * 512 + e];  // out[e*512+d]
}

// qv_bf[((b*8+h)*256+i)*64 + d] = bf16( qp[b,i,h*64+d] + v[h*64+d] )
__global__ __launch_bounds__(256) void qvb_k(const float* __restrict__ qp,
                                             const USHORT* __restrict__ vbf,
                                             USHORT* __restrict__ qv) {
  const int idx = blockIdx.x * 256 + threadIdx.x;  // 262144
  const int d = idx & 63, i = (idx >> 6) & 255, h = (idx >> 14) & 7, b = idx >> 17;
  const float q = qp[((b * 256 + i) << 9) + h * 64 + d] + bf2f(vbf[h * 64 + d]);
  qv[idx] = f2bf(q);
}

// C[m][n] = sum_k A[m,k] * W[n, koff+k]  (+bias[n])
// Direct-from-global MFMA: block = 4 waves, each wave a 16(m) x 64(n) strip.
// A-frag: A[m=lane&15][k=(lane>>4)*8+j]; B-frag: W[n=lane&15][k=(lane>>4)*8+j]
// D: col n = lane&15, row m = (lane>>4)*4 + reg   [guide §3, m89/m91-verified]
// out_mode: 0 -> f32 with z*out_z offset; 1 -> dtype per flags[0] (bf16/f32), no z.
__global__ __launch_bounds__(256) void gemm_mfma_k(
    const USHORT* __restrict__ A0, const USHORT* __restrict__ A1,
    const USHORT* __restrict__ A2, const USHORT* __restrict__ A3,
    long a_z, int lda,
    const USHORT* __restrict__ W0, const USHORT* __restrict__ W1,
    const USHORT* __restrict__ W2, const USHORT* __restrict__ W3,
    int ldw, int wkz, int wk_mod8,
    const USHORT* __restrict__ b0, const USHORT* __restrict__ b1,
    const USHORT* __restrict__ b2, const USHORT* __restrict__ b3,
    void* __restrict__ Out, long out_z, int out_mode,
    const int* __restrict__ flags, int M, int N, int K)
{
  const int z = blockIdx.z;
  const USHORT* Ap = A0; const USHORT* Wp = W0; const USHORT* bp = b0;
  if (z == 1) { Ap = A1; Wp = W1; bp = b1; }
  else if (z == 2) { Ap = A2; Wp = W2; bp = b2; }
  else if (z >= 3) { Ap = A3; Wp = W3; bp = b3; }
  Ap += (long)z * a_z;
  const int koff = (wk_mod8 ? (z & 7) : z) * wkz;

  const int wave = threadIdx.x >> 6, lane = threadIdx.x & 63;
  const int mrow = blockIdx.y * 64 + wave * 16 + (lane & 15);
  const int n0 = blockIdx.x * 64;
  const int kq = (lane >> 4) * 8;
  const bool mok = (mrow < M);
  const USHORT* ar = Ap + (long)mrow * lda + kq;
  const int nc = n0 + (lane & 15);
  const USHORT* w0p = Wp + (long)(nc +  0) * ldw + koff + kq;
  const USHORT* w1p = Wp + (long)(nc + 16) * ldw + koff + kq;
  const USHORT* w2p = Wp + (long)(nc + 32) * ldw + koff + kq;
  const USHORT* w3p = Wp + (long)(nc + 48) * ldw + koff + kq;

  f32x4 acc[4] = {};
#pragma unroll 4
  for (int k0 = 0; k0 < K; k0 += 32) {
    s8v a = {0, 0, 0, 0, 0, 0, 0, 0};
    if (mok) a = *(const s8v*)(ar + k0);
    s8v wv0 = *(const s8v*)(w0p + k0);
    s8v wv1 = *(const s8v*)(w1p + k0);
    s8v wv2 = *(const s8v*)(w2p + k0);
    s8v wv3 = *(const s8v*)(w3p + k0);
    acc[0] = __builtin_amdgcn_mfma_f32_16x16x32_bf16(a, wv0, acc[0], 0, 0, 0);
    acc[1] = __builtin_amdgcn_mfma_f32_16x16x32_bf16(a, wv1, acc[1], 0, 0, 0);
    acc[2] = __builtin_amdgcn_mfma_f32_16x16x32_bf16(a, wv2, acc[2], 0, 0, 0);
    acc[3] = __builtin_amdgcn_mfma_f32_16x16x32_bf16(a, wv3, acc[3], 0, 0, 0);
  }

  const int obf = out_mode ? flags[0] : 0;
  const int mbase = blockIdx.y * 64 + wave * 16 + (lane >> 4) * 4;
#pragma unroll
  for (int nt = 0; nt < 4; nt++) {
    const int n = n0 + nt * 16 + (lane & 15);
    const float bias = bp ? bf2f(bp[n]) : 0.f;
#pragma unroll
    for (int r = 0; r < 4; r++) {
      const int m = mbase + r;
      if (m >= M) continue;
      const float vo = acc[nt][r] + bias;
      if (out_mode) {
        const long off = (long)m * N + n;
        if (obf) ((USHORT*)Out)[off] = f2bf(vo);
        else     ((float*)Out)[off] = vo;
      } else {
        ((float*)Out)[(long)z * out_z + (long)m * N + n] = vo;
      }
    }
  }
}

// One block per (b,i). Builds relu tiles from P tables, scores, softmax, attn @ V.
__global__ __launch_bounds__(256) void score_k(
    const float* __restrict__ Ptab, const float* __restrict__ qp,
    const float* __restrict__ kp, const float* __restrict__ vp,
    const float* __restrict__ wbuf,
    const USHORT* __restrict__ u_bf, const USHORT* __restrict__ v_bf,
    const USHORT* __restrict__ bf_bf, const USHORT* __restrict__ br_bf,
    const int* __restrict__ seq_len, const int* __restrict__ lex_num,
    const int* __restrict__ pos_s, const int* __restrict__ pos_e,
    USHORT* __restrict__ out_pre_bf)
{
  __shared__ float relu_t[16 * 516];
  __shared__ float w_s[8 * 516];
  __shared__ float Sm[8 * 256];
  __shared__ float qu[8 * 68];
  __shared__ float bfv[512];
  __shared__ float part[128];
  __shared__ float red4[4];
  __shared__ float cbv[8];
  __shared__ int jidx[64];

  const int i = blockIdx.x;
  const int b = blockIdx.y;
  const int t = threadIdx.x;
  int tl = seq_len[b] + lex_num[b];
  tl = min(max(tl, 1), 256);
  const int psi = pos_s[b * 256 + i];
  const int pei = pos_e[b * 256 + i];
  const long qrow_off = (long)(b * 256 + i) * 512;

  {
    const int h = t >> 5, eb = (t & 31) * 16;
    const float* src = wbuf + (long)((b * 8 + h) * 256 + i) * 512 + eb;
#pragma unroll
    for (int m = 0; m < 4; m++)
      *(float4*)&w_s[h * 516 + eb + 4 * m] = *(const float4*)(src + 4 * m);
  }
  for (int c = t; c < 512; c += 256) {
    const int h = c >> 6, d = c & 63;
    qu[h * 68 + d] = qp[qrow_off + c] + bf2f(u_bf[c]);
    bfv[c] = bf2f(bf_bf[c]);
  }
  if (t < 8) {
    float s = 0.f;
    for (int d = 0; d < 64; d++) {
      const int c = t * 64 + d;
      s += (qp[qrow_off + c] + bf2f(v_bf[c])) * bf2f(br_bf[c]);
    }
    cbv[t] = s;
  }
  __syncthreads();

  const float* P1 = Ptab;
  const float* P2 = Ptab + 513l * 512;
  const float* P3 = Ptab + 2l * 513 * 512;
  const float* P4 = Ptab + 3l * 513 * 512;

  const int ntiles = (tl + 15) >> 4;
  for (int jt = 0; jt < ntiles; jt++) {
    const int j0 = jt * 16;
    if (t < 16) {
      const int j = j0 + t;
      const int psj = pos_s[b * 256 + j];
      const int pej = pos_e[b * 256 + j];
      jidx[0 * 16 + t] = min(max(psi - psj + 256, 0), 512);
      jidx[1 * 16 + t] = min(max(psi - pej + 256, 0), 512);
      jidx[2 * 16 + t] = min(max(pei - psj + 256, 0), 512);
      jidx[3 * 16 + t] = min(max(pei - pej + 256, 0), 512);
    }
    __syncthreads();
    {
      const int e4 = (t & 127) * 4;
      const int jh = t >> 7;
#pragma unroll
      for (int jj2 = 0; jj2 < 8; jj2++) {
        const int jl = jh * 8 + jj2;
        float4 s0 = *(const float4*)(P1 + (long)jidx[0 * 16 + jl] * 512 + e4);
        float4 s1 = *(const float4*)(P2 + (long)jidx[1 * 16 + jl] * 512 + e4);
        float4 s2 = *(const float4*)(P3 + (long)jidx[2 * 16 + jl] * 512 + e4);
        float4 s3 = *(const float4*)(P4 + (long)jidx[3 * 16 + jl] * 512 + e4);
        float4 bb = *(const float4*)&bfv[e4];
        float4 r;
        r.x = fmaxf(s0.x + s1.x + s2.x + s3.x + bb.x, 0.f);
        r.y = fmaxf(s0.y + s1.y + s2.y + s3.y + bb.y, 0.f);
        r.z = fmaxf(s0.z + s1.z + s2.z + s3.z + bb.z, 0.f);
        r.w = fmaxf(s0.w + s1.w + s2.w + s3.w + bb.w, 0.f);
        *(float4*)&relu_t[jl * 516 + e4] = r;
      }
    }
    __syncthreads();
    {
      const int pid = t & 127;
      const int h = pid & 7;
      const int jj = pid >> 3;
      const int half = t >> 7;
      const int j = j0 + jj;
      float acc = 0.f;
      if (half == 0) {
        acc = cbv[h];
        const float* krow = kp + (long)(b * 256 + j) * 512 + h * 64;
#pragma unroll
        for (int d4 = 0; d4 < 64; d4 += 4) {
          float4 k4 = *(const float4*)(krow + d4);
          float4 q4 = *(const float4*)&qu[h * 68 + d4];
          acc += k4.x * q4.x + k4.y * q4.y + k4.z * q4.z + k4.w * q4.w;
        }
      }
      const int ebase = half * 256;
#pragma unroll 8
      for (int e4 = 0; e4 < 256; e4 += 4) {
        float4 r4 = *(const float4*)&relu_t[jj * 516 + ebase + e4];
        float4 w4 = *(const float4*)&w_s[h * 516 + ebase + e4];
        acc += r4.x * w4.x + r4.y * w4.y + r4.z * w4.z + r4.w * w4.w;
      }
      if (half) part[pid] = acc;
      __syncthreads();
      if (!half) Sm[h * 256 + j] = (acc + part[pid]) * 0.125f;
    }
    __syncthreads();
  }

  const int lane = t & 63, wid = t >> 6;
  for (int h = 0; h < 8; h++) {
    const float val = (t < tl) ? Sm[h * 256 + t] : -3.0e38f;
    float m = val;
#pragma unroll
    for (int off = 32; off > 0; off >>= 1) m = fmaxf(m, __shfl_xor(m, off));
    if (lane == 0) red4[wid] = m;
    __syncthreads();
    m = fmaxf(fmaxf(red4[0], red4[1]), fmaxf(red4[2], red4[3]));
    const float p = (t < tl) ? __expf(val - m) : 0.f;
    float s = p;
#pragma unroll
    for (int off = 32; off > 0; off >>= 1) s += __shfl_xor(s, off);
    __syncthreads();
    if (lane == 0) red4[wid] = s;
    __syncthreads();
    s = red4[0] + red4[1] + red4[2] + red4[3];
    if (!(s > 1e-30f)) s = 1.f;
    Sm[h * 256 + t] = p / s;
    __syncthreads();
  }

#pragma unroll
  for (int pass = 0; pass < 2; pass++) {
    const int h = (t >> 6) + 4 * pass;
    const int d = t & 63;
    const float* vcol = vp + (long)(b * 256) * 512 + h * 64 + d;
    float acc = 0.f;
#pragma unroll 4
    for (int j = 0; j < tl; j++) acc += Sm[h * 256 + j] * vcol[(long)j * 512];
    out_pre_bf[qrow_off + h * 64 + d] = f2bf(acc);
  }
}

extern "C" void kernel_launch(void* const* d_in, const int* in_sizes, int n_in,
                              void* d_out, int out_size, void* d_ws, size_t ws_size,
                              hipStream_t stream) {
  (void)in_sizes; (void)n_in; (void)out_size; (void)ws_size;

  float* p = (float*)d_ws;
  int* flags   = (int*)p; p += 4;
  int* c_seq   = (int*)p; p += 4;
  int* c_lex   = (int*)p; p += 4;
  int* c_pos_s = (int*)p; p += 512;
  int* c_pos_e = (int*)p; p += 512;
  // canonical bf16 buffers
  USHORT* cb = (USHORT*)p;
  USHORT* c_key   = cb; cb += 262144;
  USHORT* c_query = cb; cb += 262144;
  USHORT* c_value = cb; cb += 262144;
  USHORT* c_pe    = cb; cb += 262656;
  USHORT* c_Wf    = cb; cb += 1048576;
  USHORT* c_bf    = cb; cb += 512;
  USHORT* c_Wk    = cb; cb += 262144;
  USHORT* c_bk    = cb; cb += 512;
  USHORT* c_Wq    = cb; cb += 262144;
  USHORT* c_bq    = cb; cb += 512;
  USHORT* c_Wv    = cb; cb += 262144;
  USHORT* c_bv    = cb; cb += 512;
  USHORT* c_Wr    = cb; cb += 262144;
  USHORT* c_br    = cb; cb += 512;
  USHORT* c_Wo    = cb; cb += 262144;
  USHORT* c_bo    = cb; cb += 512;
  USHORT* c_u     = cb; cb += 512;
  USHORT* c_v     = cb; cb += 512;
  USHORT* WrT        = cb; cb += 262144;
  USHORT* qv_bf      = cb; cb += 262144;
  USHORT* out_pre_bf = cb; cb += 262144;
  p += (3412480 + 3 * 262144 + 1) / 2;   // advance past USHORT region (floats)
  float* Ptab = p; p += 4l * 513 * 512;
  float* qp   = p; p += 262144;
  float* kp   = p; p += 262144;
  float* vp   = p; p += 262144;
  float* wbuf = p; p += 2097152;

  dim3 blk(256, 1, 1);
  detect_k<<<1, 64, 0, stream>>>((const USHORT*)d_in[1], flags);
  cvt_i_k<<<1, blk, 0, stream>>>(d_in[18], d_in[19], d_in[20], d_in[21],
                                 c_seq, c_lex, c_pos_s, c_pos_e);

  CvtF ca;
  USHORT* dsts[18] = {c_key, c_query, c_value, c_pe, c_Wf, c_bf, c_Wk, c_bk, c_Wq,
                      c_bq, c_Wv, c_bv, c_Wr, c_br, c_Wo, c_bo, c_u, c_v};
  int ns[18] = {262144, 262144, 262144, 262656, 1048576, 512, 262144, 512, 262144,
                512, 262144, 512, 262144, 512, 262144, 512, 512, 512};
  for (int i = 0; i < 18; i++) { ca.src[i] = d_in[i]; ca.dst[i] = dsts[i]; ca.n[i] = ns[i]; }
  cvt_f_k<<<dim3(128, 18), blk, 0, stream>>>(ca, flags);
  transp_k<<<1024, blk, 0, stream>>>(c_Wr, WrT);

  // P tables: P_t = pe @ Wf[:, t*512:(t+1)*512].T   (M=513, z=4)
  gemm_mfma_k<<<dim3(8, 9, 4), blk, 0, stream>>>(
      c_pe, c_pe, c_pe, c_pe, 0, 512,
      c_Wf, c_Wf, c_Wf, c_Wf, 2048, 512, 0,
      nullptr, nullptr, nullptr, nullptr,
      Ptab, 513l * 512, 0, flags, 513, 512, 512);
  // q/k/v projections (z=0,1,2) -> qp,kp,vp f32
  gemm_mfma_k<<<dim3(8, 8, 3), blk, 0, stream>>>(
      c_query, c_key, c_value, c_value, 0, 512,
      c_Wq, c_Wk, c_Wv, c_Wv, 512, 0, 0,
      c_bq, c_bk, c_bv, c_bv,
      qp, 262144, 0, flags, 512, 512, 512);
  // qv_bf = bf16(q + v) per (b,h,i,d)
  qvb_k<<<1024, blk, 0, stream>>>(qp, c_v, qv_bf);
  // w[b,h] = qv_bf[b,h] @ WrT[:, h*64:(h+1)*64].T  (M=256, K=64, z=16)
  gemm_mfma_k<<<dim3(8, 4, 16), blk, 0, stream>>>(
      qv_bf, qv_bf, qv_bf, qv_bf, 16384, 64,
      WrT, WrT, WrT, WrT, 512, 64, 1,
      nullptr, nullptr, nullptr, nullptr,
      wbuf, 131072, 0, flags, 256, 512, 64);
  // scores + softmax + attn@V  -> out_pre_bf
  score_k<<<dim3(256, 2), blk, 0, stream>>>(
      Ptab, qp, kp, vp, wbuf, c_u, c_v, c_bf, c_br,
      c_seq, c_lex, c_pos_s, c_pos_e, out_pre_bf);
  // final: out = out_pre @ Wo.T + bo -> d_out (dtype per flags[0])
  gemm_mfma_k<<<dim3(8, 8, 1), blk, 0, stream>>>(
      out_pre_bf, out_pre_bf, out_pre_bf, out_pre_bf, 0, 512,
      c_Wo, c_Wo, c_Wo, c_Wo, 512, 0, 0,
      c_bo, c_bo, c_bo, c_bo,
      d_out, 0, 1, flags, 512, 512, 512);
}

// Round 6
// 247.362 us; speedup vs baseline: 1.3665x; 1.1474x over previous
//
#include <hip/hip_runtime.h>
#include <hip/hip_bf16.h>

typedef unsigned short USHORT;
typedef long long LL;
typedef short s8v __attribute__((ext_vector_type(8)));
typedef float f32x4 __attribute__((ext_vector_type(4)));

// B=2, L=256, H=512, NH=8, DH=64, MAXLEN=256, PE_ROWS=513
// Dtypes runtime-detected: floats f32-or-bf16 (canonicalized to bf16), ints i32-or-i64.

__device__ __forceinline__ float bf2f(USHORT u) {
  union { unsigned int i; float f; } v; v.i = ((unsigned int)u) << 16; return v.f;
}
__device__ __forceinline__ USHORT f2bf(float f) {
  unsigned int x = __float_as_uint(f);
  unsigned int r = (x + 0x7fffu + ((x >> 16) & 1u)) >> 16;
  return (USHORT)r;
}

// ---------------- preamble: dtype-detect + canonicalize + transpose + ints ----
struct PrepArgs {
  const void* fsrc[18]; USHORT* fdst[18]; int fn[18];
  const void* wr_src; USHORT* wrT;
  const void* isrc[4]; int* idst[4];
};

__global__ __launch_bounds__(256) void prep_k(PrepArgs a, const void* qraw, int* flags) {
  __shared__ int s_w;
  const int t = threadIdx.x;
  if (t == 0) s_w = 0;
  __syncthreads();
  const USHORT* qb = (const USHORT*)qraw;
  int wild = 0;
  for (int c = t; c < 512; c += 256) {
    float x = bf2f(qb[c]);
    if (!(fabsf(x) <= 1024.0f)) wild = 1;  // catches NaN too
  }
  if (wild) atomicAdd(&s_w, 1);
  __syncthreads();
  const int f = (s_w == 0) ? 1 : 0;  // 1 iff float inputs are bf16

  const int y = blockIdx.y;
  if (y < 18) {
    const int n = a.fn[y];
    const USHORT* sb = (const USHORT*)a.fsrc[y];
    const float* sf = (const float*)a.fsrc[y];
    USHORT* d = a.fdst[y];
    for (int idx = blockIdx.x * 256 + t; idx < n; idx += gridDim.x * 256)
      d[idx] = f ? sb[idx] : f2bf(sf[idx]);
  } else if (y == 18) {
    const USHORT* sb = (const USHORT*)a.wr_src;
    const float* sf = (const float*)a.wr_src;
    for (int idx = blockIdx.x * 256 + t; idx < 262144; idx += gridDim.x * 256) {
      const int e = idx >> 9, dd = idx & 511;
      const int s = dd * 512 + e;
      a.wrT[idx] = f ? sb[s] : f2bf(sf[s]);  // WrT[e][d] = Wr[d][e]
    }
  } else if (blockIdx.x == 0) {
    if (t == 0) flags[0] = f;
    const int fi = (((const int*)a.isrc[0])[1] == 0) ? 1 : 0;  // seq_len[0] in [100,200)
    if (t < 2) {
      a.idst[0][t] = fi ? (int)((const LL*)a.isrc[0])[t] : ((const int*)a.isrc[0])[t];
      a.idst[1][t] = fi ? (int)((const LL*)a.isrc[1])[t] : ((const int*)a.isrc[1])[t];
    }
    for (int c = t; c < 512; c += 256) {
      a.idst[2][c] = fi ? (int)((const LL*)a.isrc[2])[c] : ((const int*)a.isrc[2])[c];
      a.idst[3][c] = fi ? (int)((const LL*)a.isrc[3])[c] : ((const int*)a.isrc[3])[c];
    }
  }
}

// ---------------- generic multi-desc MFMA GEMM: C[m][n] = sum_k A[m,k]*W[n,koff+k] (+bias)
struct GDesc {
  const USHORT* A; const USHORT* W; const USHORT* bias;
  void* out;
  int M, N, K, lda, ldw, koff, mode;  // mode: 0 f32, 1 bf16, 2 per-flag dtype
};
struct GArgs { GDesc d[32]; };

__global__ __launch_bounds__(256) void gemm2_k(GArgs ga, const int* __restrict__ flags) {
  const GDesc de = ga.d[blockIdx.z];
  const int row0 = blockIdx.y * 64, col0 = blockIdx.x * 64;
  if (row0 >= de.M || col0 >= de.N) return;
  const int wave = threadIdx.x >> 6, lane = threadIdx.x & 63;
  const int mrow = row0 + wave * 16 + (lane & 15);
  const int kq = (lane >> 4) * 8;
  const bool mok = (mrow < de.M);
  const USHORT* ar = de.A + (long)(mok ? mrow : 0) * de.lda + kq;
  const int nc = col0 + (lane & 15);
  const USHORT* w0p = de.W + (long)(nc +  0) * de.ldw + de.koff + kq;
  const USHORT* w1p = de.W + (long)(nc + 16) * de.ldw + de.koff + kq;
  const USHORT* w2p = de.W + (long)(nc + 32) * de.ldw + de.koff + kq;
  const USHORT* w3p = de.W + (long)(nc + 48) * de.ldw + de.koff + kq;

  f32x4 acc[4] = {};
#pragma unroll 4
  for (int k0 = 0; k0 < de.K; k0 += 32) {
    s8v a = *(const s8v*)(ar + k0);
    s8v wv0 = *(const s8v*)(w0p + k0);
    s8v wv1 = *(const s8v*)(w1p + k0);
    s8v wv2 = *(const s8v*)(w2p + k0);
    s8v wv3 = *(const s8v*)(w3p + k0);
    acc[0] = __builtin_amdgcn_mfma_f32_16x16x32_bf16(a, wv0, acc[0], 0, 0, 0);
    acc[1] = __builtin_amdgcn_mfma_f32_16x16x32_bf16(a, wv1, acc[1], 0, 0, 0);
    acc[2] = __builtin_amdgcn_mfma_f32_16x16x32_bf16(a, wv2, acc[2], 0, 0, 0);
    acc[3] = __builtin_amdgcn_mfma_f32_16x16x32_bf16(a, wv3, acc[3], 0, 0, 0);
  }

  const int obf = (de.mode == 2) ? flags[0] : (de.mode == 1);
  const int mbase = row0 + wave * 16 + (lane >> 4) * 4;
#pragma unroll
  for (int nt = 0; nt < 4; nt++) {
    const int n = col0 + nt * 16 + (lane & 15);
    const float bias = de.bias ? bf2f(de.bias[n]) : 0.f;
#pragma unroll
    for (int r = 0; r < 4; r++) {
      const int m = mbase + r;
      if (m >= de.M) continue;
      const float vo = acc[nt][r] + bias;
      const long off = (long)m * de.N + n;
      if (obf) ((USHORT*)de.out)[off] = f2bf(vo);
      else     ((float*)de.out)[off] = vo;
    }
  }
}

// ---------------- rearrange: qv/qu/k to [b,h,row,d] bf16 + cbv wave-reduction ----
__global__ __launch_bounds__(256) void qvb2_k(
    const float* __restrict__ qp, const float* __restrict__ kp,
    const USHORT* __restrict__ u_bf, const USHORT* __restrict__ v_bf,
    const USHORT* __restrict__ br_bf,
    USHORT* __restrict__ qv, USHORT* __restrict__ qu, USHORT* __restrict__ kb,
    float* __restrict__ cbv_buf)
{
  const int idx = blockIdx.x * 256 + threadIdx.x;  // 262144
  const int d = idx & 63, i = (idx >> 6) & 255, h = (idx >> 14) & 7, b = idx >> 17;
  const int hd = h * 64 + d;
  const long row = (long)(b * 256 + i) * 512 + hd;
  const float q = qp[row];
  const float qpv = q + bf2f(v_bf[hd]);
  qv[idx] = f2bf(qpv);
  qu[idx] = f2bf(q + bf2f(u_bf[hd]));
  kb[idx] = f2bf(kp[row]);
  float s = qpv * bf2f(br_bf[hd]);
#pragma unroll
  for (int off = 32; off > 0; off >>= 1) s += __shfl_xor(s, off);
  if ((threadIdx.x & 63) == 0) cbv_buf[idx >> 6] = s;
}

// ---------------- score: per-wave MFMA relu-dot, softmax, attn@V ----------------
// block (i, b), 4 waves; each wave owns j-tiles jt = wave, wave+4, ...
__global__ __launch_bounds__(256) void score2_k(
    const USHORT* __restrict__ Ptab_bf, const float* __restrict__ S_AC,
    const float* __restrict__ cbv_buf, const USHORT* __restrict__ wbuf_bf,
    const float* __restrict__ vp,
    const int* __restrict__ seq_len, const int* __restrict__ lex_num,
    const int* __restrict__ pos_s, const int* __restrict__ pos_e,
    USHORT* __restrict__ out_pre_bf)
{
  __shared__ float Sm[8 * 257];
  __shared__ int psj_s[256], pej_s[256];
  __shared__ float red4[4];

  const int i = blockIdx.x, b = blockIdx.y, t = threadIdx.x;
  const int wave = t >> 6, lane = t & 63;
  const int n = lane & 15, q = lane >> 4;
  int tl = seq_len[b] + lex_num[b];
  tl = min(max(tl, 1), 256);
  const int psi = pos_s[b * 256 + i];
  const int pei = pos_e[b * 256 + i];

  if (t < 256) { psj_s[t] = pos_s[b * 256 + t]; pej_s[t] = pos_e[b * 256 + t]; }

  // w B-fragments (per lane, resident in VGPRs): B[n=h][k=kk*32+q*8+..]
  s8v wf[16];
  if (n < 8) {
    const USHORT* wr = wbuf_bf + ((long)((b * 8 + n) * 256 + i)) * 512 + q * 8;
#pragma unroll
    for (int kk = 0; kk < 16; kk++) wf[kk] = *(const s8v*)(wr + kk * 32);
  } else {
#pragma unroll
    for (int kk = 0; kk < 16; kk++) wf[kk] = (s8v){0, 0, 0, 0, 0, 0, 0, 0};
  }
  __syncthreads();

  const USHORT* P1 = Ptab_bf;                    // includes +bf bias
  const USHORT* P2 = Ptab_bf + 513l * 512;
  const USHORT* P3 = Ptab_bf + 2l * 513 * 512;
  const USHORT* P4 = Ptab_bf + 3l * 513 * 512;

  const int ntiles = (tl + 15) >> 4;
  for (int jt = wave; jt < ntiles; jt += 4) {
    const int j0 = jt * 16;
    const int j = j0 + n;                        // A-row m = n = lane&15
    const int psj = psj_s[j], pej = pej_s[j];
    const long i0 = (long)min(max(psi - psj + 256, 0), 512) * 512 + q * 8;
    const long i1 = (long)min(max(psi - pej + 256, 0), 512) * 512 + q * 8;
    const long i2 = (long)min(max(pei - psj + 256, 0), 512) * 512 + q * 8;
    const long i3 = (long)min(max(pei - pej + 256, 0), 512) * 512 + q * 8;
    f32x4 acc = {0.f, 0.f, 0.f, 0.f};
#pragma unroll
    for (int kk = 0; kk < 16; kk++) {
      const int e0 = kk * 32;
      s8v a0 = *(const s8v*)(P1 + i0 + e0);
      s8v a1 = *(const s8v*)(P2 + i1 + e0);
      s8v a2 = *(const s8v*)(P3 + i2 + e0);
      s8v a3 = *(const s8v*)(P4 + i3 + e0);
      s8v af;
#pragma unroll
      for (int x = 0; x < 8; x++) {
        const float fs = bf2f((USHORT)a0[x]) + bf2f((USHORT)a1[x]) +
                         bf2f((USHORT)a2[x]) + bf2f((USHORT)a3[x]);
        af[x] = (short)f2bf(fmaxf(fs, 0.f));
      }
      acc = __builtin_amdgcn_mfma_f32_16x16x32_bf16(af, wf[kk], acc, 0, 0, 0);
    }
    // D: col h = lane&15, row j_local = q*4+r
    if (n < 8) {
      const long base = (long)(b * 8 + n) * 256 + i;
      const float cb = cbv_buf[base];
      const float4 sac = *(const float4*)(S_AC + base * 256 + j0 + q * 4);
      const float* sacp = (const float*)&sac;
#pragma unroll
      for (int r = 0; r < 4; r++)
        Sm[n * 257 + j0 + q * 4 + r] = (acc[r] + sacp[r] + cb) * 0.125f;
    }
  }
  __syncthreads();

  // softmax over j per (h): 256 threads = one j each
  for (int h = 0; h < 8; h++) {
    const float val = (t < tl) ? Sm[h * 257 + t] : -3.0e38f;
    float m = val;
#pragma unroll
    for (int off = 32; off > 0; off >>= 1) m = fmaxf(m, __shfl_xor(m, off));
    if (lane == 0) red4[wave] = m;
    __syncthreads();
    m = fmaxf(fmaxf(red4[0], red4[1]), fmaxf(red4[2], red4[3]));
    const float pv = (t < tl) ? __expf(val - m) : 0.f;
    float s = pv;
#pragma unroll
    for (int off = 32; off > 0; off >>= 1) s += __shfl_xor(s, off);
    __syncthreads();
    if (lane == 0) red4[wave] = s;
    __syncthreads();
    s = red4[0] + red4[1] + red4[2] + red4[3];
    if (!(s > 1e-30f)) s = 1.f;
    Sm[h * 257 + t] = pv / s;
    __syncthreads();
  }

  // attn @ V
#pragma unroll
  for (int pass = 0; pass < 2; pass++) {
    const int h = (t >> 6) + 4 * pass;
    const int d = t & 63;
    const float* vcol = vp + (long)(b * 256) * 512 + h * 64 + d;
    float acc = 0.f;
#pragma unroll 4
    for (int j = 0; j < tl; j++) acc += Sm[h * 257 + j] * vcol[(long)j * 512];
    out_pre_bf[(long)(b * 256 + i) * 512 + h * 64 + d] = f2bf(acc);
  }
}

extern "C" void kernel_launch(void* const* d_in, const int* in_sizes, int n_in,
                              void* d_out, int out_size, void* d_ws, size_t ws_size,
                              hipStream_t stream) {
  (void)in_sizes; (void)n_in; (void)out_size; (void)ws_size;

  float* p = (float*)d_ws;
  int* flags   = (int*)p; p += 4;
  int* c_seq   = (int*)p; p += 4;
  int* c_lex   = (int*)p; p += 4;
  int* c_pos_s = (int*)p; p += 512;
  int* c_pos_e = (int*)p; p += 512;
  USHORT* cb = (USHORT*)p;
  USHORT* c_key   = cb; cb += 262144;
  USHORT* c_query = cb; cb += 262144;
  USHORT* c_value = cb; cb += 262144;
  USHORT* c_pe    = cb; cb += 262656;
  USHORT* c_Wf    = cb; cb += 1048576;
  USHORT* c_bf    = cb; cb += 512;
  USHORT* c_Wk    = cb; cb += 262144;
  USHORT* c_bk    = cb; cb += 512;
  USHORT* c_Wq    = cb; cb += 262144;
  USHORT* c_bq    = cb; cb += 512;
  USHORT* c_Wv    = cb; cb += 262144;
  USHORT* c_bv    = cb; cb += 512;
  USHORT* c_Wr    = cb; cb += 262144;
  USHORT* c_br    = cb; cb += 512;
  USHORT* c_Wo    = cb; cb += 262144;
  USHORT* c_bo    = cb; cb += 512;
  USHORT* c_u     = cb; cb += 512;
  USHORT* c_v     = cb; cb += 512;
  USHORT* WrT        = cb; cb += 262144;
  USHORT* qv_bf      = cb; cb += 262144;  // [b,h,i,d]
  USHORT* qu_bf      = cb; cb += 262144;  // [b,h,i,d]
  USHORT* k_bf       = cb; cb += 262144;  // [b,h,j,d]
  USHORT* wbuf_bf    = cb; cb += 2097152; // [b,h,i,e]
  USHORT* Ptab_bf    = cb; cb += 1050624; // 4 tables x 513 x 512
  USHORT* out_pre_bf = cb; cb += 262144;
  p += 3935488;  // past 7,870,976 ushorts
  float* qp      = p; p += 262144;
  float* kp      = p; p += 262144;
  float* vp      = p; p += 262144;
  float* S_AC    = p; p += 1048576;  // [b,h,i,j] f32
  float* cbv_buf = p; p += 4096;

  // 1) preamble
  PrepArgs pa;
  USHORT* dsts[18] = {c_key, c_query, c_value, c_pe, c_Wf, c_bf, c_Wk, c_bk, c_Wq,
                      c_bq, c_Wv, c_bv, c_Wr, c_br, c_Wo, c_bo, c_u, c_v};
  int ns[18] = {262144, 262144, 262144, 262656, 1048576, 512, 262144, 512, 262144,
                512, 262144, 512, 262144, 512, 262144, 512, 512, 512};
  for (int i = 0; i < 18; i++) { pa.fsrc[i] = d_in[i]; pa.fdst[i] = dsts[i]; pa.fn[i] = ns[i]; }
  pa.wr_src = d_in[12]; pa.wrT = WrT;
  for (int i = 0; i < 4; i++) pa.isrc[i] = d_in[18 + i];
  pa.idst[0] = c_seq; pa.idst[1] = c_lex; pa.idst[2] = c_pos_s; pa.idst[3] = c_pos_e;
  prep_k<<<dim3(64, 20), 256, 0, stream>>>(pa, d_in[1], flags);

  // 2) P tables (bf16, +bf folded into table 0) + q/k/v projections (f32)
  GArgs gA = {};
  for (int z = 0; z < 4; z++)
    gA.d[z] = {c_pe, c_Wf, (z == 0) ? c_bf : nullptr, Ptab_bf + (long)z * 513 * 512,
               513, 512, 512, 512, 2048, z * 512, 1};
  gA.d[4] = {c_query, c_Wq, c_bq, qp, 512, 512, 512, 512, 512, 0, 0};
  gA.d[5] = {c_key,   c_Wk, c_bk, kp, 512, 512, 512, 512, 512, 0, 0};
  gA.d[6] = {c_value, c_Wv, c_bv, vp, 512, 512, 512, 512, 512, 0, 0};
  gemm2_k<<<dim3(8, 9, 7), 256, 0, stream>>>(gA, flags);

  // 3) rearrange + cbv
  qvb2_k<<<1024, 256, 0, stream>>>(qp, kp, c_u, c_v, c_br, qv_bf, qu_bf, k_bf, cbv_buf);

  // 4) wproj (bf16) + S_AC (f32), fused dispatch
  GArgs gB = {};
  for (int z = 0; z < 16; z++)
    gB.d[z] = {qv_bf + z * 16384, WrT, nullptr, wbuf_bf + (long)z * 131072,
               256, 512, 64, 64, 512, (z & 7) * 64, 1};
  for (int z = 0; z < 16; z++)
    gB.d[16 + z] = {qu_bf + z * 16384, k_bf + z * 16384, nullptr, S_AC + (long)z * 65536,
                    256, 256, 64, 64, 64, 0, 0};
  gemm2_k<<<dim3(8, 4, 32), 256, 0, stream>>>(gB, flags);

  // 5) scores + softmax + attn@V
  score2_k<<<dim3(256, 2), 256, 0, stream>>>(
      Ptab_bf, S_AC, cbv_buf, wbuf_bf, vp,
      c_seq, c_lex, c_pos_s, c_pos_e, out_pre_bf);

  // 6) final: out = out_pre @ Wo.T + bo -> d_out (dtype per flag)
  GArgs gC = {};
  gC.d[0] = {out_pre_bf, c_Wo, c_bo, d_out, 512, 512, 512, 512, 512, 0, 2};
  gemm2_k<<<dim3(8, 8, 1), 256, 0, stream>>>(gC, flags);
}

// Round 7
// 238.861 us; speedup vs baseline: 1.4152x; 1.0356x over previous
//
#include <hip/hip_runtime.h>
#include <hip/hip_bf16.h>

typedef unsigned short USHORT;
typedef long long LL;
typedef short s8v __attribute__((ext_vector_type(8)));
typedef float f32x4 __attribute__((ext_vector_type(4)));

// B=2, L=256, H=512, NH=8, DH=64, MAXLEN=256, PE_ROWS=513
// Dtypes runtime-detected: floats f32-or-bf16 (canonicalized to bf16), ints i32-or-i64.

__device__ __forceinline__ float bf2f(USHORT u) {
  union { unsigned int i; float f; } v; v.i = ((unsigned int)u) << 16; return v.f;
}
__device__ __forceinline__ USHORT f2bf(float f) {
  unsigned int x = __float_as_uint(f);
  unsigned int r = (x + 0x7fffu + ((x >> 16) & 1u)) >> 16;
  return (USHORT)r;
}

// ---------------- preamble: dtype-detect + canonicalize + transpose + ints ----
struct PrepArgs {
  const void* fsrc[18]; USHORT* fdst[18]; int fn[18];
  const void* wr_src; USHORT* wrT;
  const void* isrc[4]; int* idst[4];
};

__global__ __launch_bounds__(256) void prep_k(PrepArgs a, const void* qraw, int* flags) {
  __shared__ int s_w;
  const int t = threadIdx.x;
  if (t == 0) s_w = 0;
  __syncthreads();
  const USHORT* qb = (const USHORT*)qraw;
  int wild = 0;
  for (int c = t; c < 512; c += 256) {
    float x = bf2f(qb[c]);
    if (!(fabsf(x) <= 1024.0f)) wild = 1;  // catches NaN too
  }
  if (wild) atomicAdd(&s_w, 1);
  __syncthreads();
  const int f = (s_w == 0) ? 1 : 0;  // 1 iff float inputs are bf16

  const int y = blockIdx.y;
  if (y < 18) {
    const int n = a.fn[y];
    const USHORT* sb = (const USHORT*)a.fsrc[y];
    const float* sf = (const float*)a.fsrc[y];
    USHORT* d = a.fdst[y];
    for (int idx = blockIdx.x * 256 + t; idx < n; idx += gridDim.x * 256)
      d[idx] = f ? sb[idx] : f2bf(sf[idx]);
  } else if (y == 18) {
    const USHORT* sb = (const USHORT*)a.wr_src;
    const float* sf = (const float*)a.wr_src;
    for (int idx = blockIdx.x * 256 + t; idx < 262144; idx += gridDim.x * 256) {
      const int e = idx >> 9, dd = idx & 511;
      const int s = dd * 512 + e;
      a.wrT[idx] = f ? sb[s] : f2bf(sf[s]);  // WrT[e][d] = Wr[d][e]
    }
  } else if (blockIdx.x == 0) {
    if (t == 0) flags[0] = f;
    const int fi = (((const int*)a.isrc[0])[1] == 0) ? 1 : 0;  // seq_len[0] in [100,200)
    if (t < 2) {
      a.idst[0][t] = fi ? (int)((const LL*)a.isrc[0])[t] : ((const int*)a.isrc[0])[t];
      a.idst[1][t] = fi ? (int)((const LL*)a.isrc[1])[t] : ((const int*)a.isrc[1])[t];
    }
    for (int c = t; c < 512; c += 256) {
      a.idst[2][c] = fi ? (int)((const LL*)a.isrc[2])[c] : ((const int*)a.isrc[2])[c];
      a.idst[3][c] = fi ? (int)((const LL*)a.isrc[3])[c] : ((const int*)a.isrc[3])[c];
    }
  }
}

// ---------------- generic multi-desc MFMA GEMM: C[m][n] = sum_k A[m,k]*W[n,koff+k] (+bias)
// mode: 0 f32, 1 bf16, 2 per-flag dtype.  trans: store C^T at n*ldo+m (else m*ldo+n).
struct GDesc {
  const USHORT* A; const USHORT* W; const USHORT* bias;
  void* out;
  int M, N, K, lda, ldw, koff, ldo, mode, trans, pad;
};
struct GArgs { GDesc d[32]; };

__global__ __launch_bounds__(256) void gemm2_k(GArgs ga, const int* __restrict__ flags) {
  const GDesc de = ga.d[blockIdx.z];
  const int row0 = blockIdx.y * 64, col0 = blockIdx.x * 64;
  if (row0 >= de.M || col0 >= de.N) return;
  const int wave = threadIdx.x >> 6, lane = threadIdx.x & 63;
  const int mrow = row0 + wave * 16 + (lane & 15);
  const int kq = (lane >> 4) * 8;
  const bool mok = (mrow < de.M);
  const USHORT* ar = de.A + (long)(mok ? mrow : 0) * de.lda + kq;
  const int nc = col0 + (lane & 15);
  const USHORT* w0p = de.W + (long)(nc +  0) * de.ldw + de.koff + kq;
  const USHORT* w1p = de.W + (long)(nc + 16) * de.ldw + de.koff + kq;
  const USHORT* w2p = de.W + (long)(nc + 32) * de.ldw + de.koff + kq;
  const USHORT* w3p = de.W + (long)(nc + 48) * de.ldw + de.koff + kq;

  f32x4 acc[4] = {};
#pragma unroll 4
  for (int k0 = 0; k0 < de.K; k0 += 32) {
    s8v a = *(const s8v*)(ar + k0);
    s8v wv0 = *(const s8v*)(w0p + k0);
    s8v wv1 = *(const s8v*)(w1p + k0);
    s8v wv2 = *(const s8v*)(w2p + k0);
    s8v wv3 = *(const s8v*)(w3p + k0);
    acc[0] = __builtin_amdgcn_mfma_f32_16x16x32_bf16(a, wv0, acc[0], 0, 0, 0);
    acc[1] = __builtin_amdgcn_mfma_f32_16x16x32_bf16(a, wv1, acc[1], 0, 0, 0);
    acc[2] = __builtin_amdgcn_mfma_f32_16x16x32_bf16(a, wv2, acc[2], 0, 0, 0);
    acc[3] = __builtin_amdgcn_mfma_f32_16x16x32_bf16(a, wv3, acc[3], 0, 0, 0);
  }

  const int obf = (de.mode == 2) ? flags[0] : (de.mode == 1);
  const int mbase = row0 + wave * 16 + (lane >> 4) * 4;
#pragma unroll
  for (int nt = 0; nt < 4; nt++) {
    const int n = col0 + nt * 16 + (lane & 15);
    const float bias = de.bias ? bf2f(de.bias[n]) : 0.f;
#pragma unroll
    for (int r = 0; r < 4; r++) {
      const int m = mbase + r;
      if (m >= de.M) continue;
      const float vo = acc[nt][r] + bias;
      const long off = de.trans ? ((long)n * de.ldo + m) : ((long)m * de.ldo + n);
      if (obf) ((USHORT*)de.out)[off] = f2bf(vo);
      else     ((float*)de.out)[off] = vo;
    }
  }
}

// ---------------- elementwise: qv/qu (bf16, normal layout) + cbv wave-reduction ----
__global__ __launch_bounds__(256) void qvb3_k(
    const USHORT* __restrict__ q_n,
    const USHORT* __restrict__ u_bf, const USHORT* __restrict__ v_bf,
    const USHORT* __restrict__ br_bf,
    USHORT* __restrict__ qv_n, USHORT* __restrict__ qu_n,
    float* __restrict__ cbv_buf)
{
  const int idx = blockIdx.x * 256 + threadIdx.x;  // 262144
  const int hd = idx & 511;
  const float qv = bf2f(q_n[idx]);
  const float qpv = qv + bf2f(v_bf[hd]);
  qv_n[idx] = f2bf(qpv);
  qu_n[idx] = f2bf(qv + bf2f(u_bf[hd]));
  float s = qpv * bf2f(br_bf[hd]);
#pragma unroll
  for (int off = 32; off > 0; off >>= 1) s += __shfl_xor(s, off);
  if ((threadIdx.x & 63) == 0) cbv_buf[idx >> 6] = s;  // [b,i,h]
}

// ---------------- scoring: one wave per (b, i, j-tile); no LDS, no barriers ----
__global__ __launch_bounds__(128) void score3_k(
    const USHORT* __restrict__ Ptab_bf, const float* __restrict__ S_AC,
    const float* __restrict__ cbv_buf, const USHORT* __restrict__ wbuf_bf,
    const int* __restrict__ seq_len, const int* __restrict__ lex_num,
    const int* __restrict__ pos_s, const int* __restrict__ pos_e,
    float* __restrict__ S_full)
{
  const int i = blockIdx.x, b = blockIdx.y;
  const int wave = threadIdx.x >> 6, lane = threadIdx.x & 63;
  const int jt = blockIdx.z * 2 + wave;
  int tl = seq_len[b] + lex_num[b];
  tl = min(max(tl, 1), 256);
  const int j0 = jt * 16;
  if (j0 >= tl) return;
  const int n = lane & 15, q = lane >> 4;
  const int psi = pos_s[b * 256 + i], pei = pos_e[b * 256 + i];
  const int j = j0 + n;
  const int psj = pos_s[b * 256 + j], pej = pos_e[b * 256 + j];

  const USHORT* P1 = Ptab_bf;                    // includes +bf bias
  const USHORT* P2 = Ptab_bf + 513l * 512;
  const USHORT* P3 = Ptab_bf + 2l * 513 * 512;
  const USHORT* P4 = Ptab_bf + 3l * 513 * 512;
  const USHORT* g0 = P1 + (long)min(max(psi - psj + 256, 0), 512) * 512 + q * 8;
  const USHORT* g1 = P2 + (long)min(max(psi - pej + 256, 0), 512) * 512 + q * 8;
  const USHORT* g2 = P3 + (long)min(max(pei - psj + 256, 0), 512) * 512 + q * 8;
  const USHORT* g3 = P4 + (long)min(max(pei - pej + 256, 0), 512) * 512 + q * 8;
  const USHORT* wr = wbuf_bf + ((long)((b * 8 + (n & 7)) * 256 + i)) * 512 + q * 8;

  f32x4 acc = {0.f, 0.f, 0.f, 0.f};
#pragma unroll 4
  for (int kk = 0; kk < 16; kk++) {
    const int e0 = kk * 32;
    s8v a0 = *(const s8v*)(g0 + e0);
    s8v a1 = *(const s8v*)(g1 + e0);
    s8v a2 = *(const s8v*)(g2 + e0);
    s8v a3 = *(const s8v*)(g3 + e0);
    s8v wv = (s8v){0, 0, 0, 0, 0, 0, 0, 0};
    if (n < 8) wv = *(const s8v*)(wr + e0);
    s8v af;
#pragma unroll
    for (int x = 0; x < 8; x++) {
      float fs = bf2f((USHORT)a0[x]) + bf2f((USHORT)a1[x]) +
                 bf2f((USHORT)a2[x]) + bf2f((USHORT)a3[x]);
      fs = fmaxf(fs, 0.f);
      af[x] = (short)(USHORT)((__float_as_uint(fs) + 0x8000u) >> 16);
    }
    acc = __builtin_amdgcn_mfma_f32_16x16x32_bf16(af, wv, acc, 0, 0, 0);
  }
  // D: col h = lane&15 (h<8 valid), row j_local = q*4 + r
  if (n < 8) {
    const long base = (long)(b * 8 + n) * 256 + i;
    const float cb = cbv_buf[(long)(b * 256 + i) * 8 + n];
    const float4 sac = *(const float4*)(S_AC + base * 256 + j0 + q * 4);
    float* dst = S_full + base * 256 + j0 + q * 4;
    dst[0] = (acc[0] + sac.x + cb) * 0.125f;
    dst[1] = (acc[1] + sac.y + cb) * 0.125f;
    dst[2] = (acc[2] + sac.z + cb) * 0.125f;
    dst[3] = (acc[3] + sac.w + cb) * 0.125f;
  }
}

// ---------------- softmax: per (b,i), 256 threads = one j each ----------------
__global__ __launch_bounds__(256) void softmax_k(
    const float* __restrict__ S_full,
    const int* __restrict__ seq_len, const int* __restrict__ lex_num,
    USHORT* __restrict__ attn_bf)
{
  __shared__ float red4[4];
  const int i = blockIdx.x, b = blockIdx.y, t = threadIdx.x;
  const int lane = t & 63, wave = t >> 6;
  int tl = seq_len[b] + lex_num[b];
  tl = min(max(tl, 1), 256);
  for (int h = 0; h < 8; h++) {
    const long base = ((long)(b * 8 + h) * 256 + i) * 256;
    const float val = (t < tl) ? S_full[base + t] : -3.0e38f;
    float m = val;
#pragma unroll
    for (int off = 32; off > 0; off >>= 1) m = fmaxf(m, __shfl_xor(m, off));
    if (lane == 0) red4[wave] = m;
    __syncthreads();
    m = fmaxf(fmaxf(red4[0], red4[1]), fmaxf(red4[2], red4[3]));
    const float pv = (t < tl) ? __expf(val - m) : 0.f;
    float s = pv;
#pragma unroll
    for (int off = 32; off > 0; off >>= 1) s += __shfl_xor(s, off);
    __syncthreads();
    if (lane == 0) red4[wave] = s;
    __syncthreads();
    s = red4[0] + red4[1] + red4[2] + red4[3];
    if (!(s > 1e-30f)) s = 1.f;
    attn_bf[base + t] = f2bf(pv / s);
    __syncthreads();
  }
}

extern "C" void kernel_launch(void* const* d_in, const int* in_sizes, int n_in,
                              void* d_out, int out_size, void* d_ws, size_t ws_size,
                              hipStream_t stream) {
  (void)in_sizes; (void)n_in; (void)out_size; (void)ws_size;

  float* fp = (float*)d_ws;
  int* flags   = (int*)fp; fp += 4;
  int* c_seq   = (int*)fp; fp += 4;
  int* c_lex   = (int*)fp; fp += 4;
  int* c_pos_s = (int*)fp; fp += 512;
  int* c_pos_e = (int*)fp; fp += 512;
  USHORT* cb = (USHORT*)fp;
  USHORT* c_key   = cb; cb += 262144;
  USHORT* c_query = cb; cb += 262144;
  USHORT* c_value = cb; cb += 262144;
  USHORT* c_pe    = cb; cb += 262656;
  USHORT* c_Wf    = cb; cb += 1048576;
  USHORT* c_bf    = cb; cb += 512;
  USHORT* c_Wk    = cb; cb += 262144;
  USHORT* c_bk    = cb; cb += 512;
  USHORT* c_Wq    = cb; cb += 262144;
  USHORT* c_bq    = cb; cb += 512;
  USHORT* c_Wv    = cb; cb += 262144;
  USHORT* c_bv    = cb; cb += 512;
  USHORT* c_Wr    = cb; cb += 262144;
  USHORT* c_br    = cb; cb += 512;
  USHORT* c_Wo    = cb; cb += 262144;
  USHORT* c_bo    = cb; cb += 512;
  USHORT* c_u     = cb; cb += 512;
  USHORT* c_v     = cb; cb += 512;
  USHORT* WrT        = cb; cb += 262144;  // [e][d]
  USHORT* q_n        = cb; cb += 262144;  // [b*256+i][512]
  USHORT* k_n        = cb; cb += 262144;  // [b*256+j][512]
  USHORT* v_t        = cb; cb += 262144;  // [h*64+d][b*256+j]
  USHORT* qv_n       = cb; cb += 262144;
  USHORT* qu_n       = cb; cb += 262144;
  USHORT* wbuf_bf    = cb; cb += 2097152; // [b,h,i,e]
  USHORT* Ptab_bf    = cb; cb += 1050624; // 4 x 513 x 512
  USHORT* attn_bf    = cb; cb += 1048576; // [b,h,i,j]
  USHORT* out_pre_bf = cb; cb += 262144;  // [b*256+i][512]
  float* gp = (float*)cb;
  float* S_AC    = gp; gp += 1048576;  // [b,h,i,j]
  float* S_full  = gp; gp += 1048576;  // [b,h,i,j]
  float* cbv_buf = gp; gp += 4096;     // [b,i,h]

  // 1) preamble
  PrepArgs pa;
  USHORT* dsts[18] = {c_key, c_query, c_value, c_pe, c_Wf, c_bf, c_Wk, c_bk, c_Wq,
                      c_bq, c_Wv, c_bv, c_Wr, c_br, c_Wo, c_bo, c_u, c_v};
  int ns[18] = {262144, 262144, 262144, 262656, 1048576, 512, 262144, 512, 262144,
                512, 262144, 512, 262144, 512, 262144, 512, 512, 512};
  for (int i = 0; i < 18; i++) { pa.fsrc[i] = d_in[i]; pa.fdst[i] = dsts[i]; pa.fn[i] = ns[i]; }
  pa.wr_src = d_in[12]; pa.wrT = WrT;
  for (int i = 0; i < 4; i++) pa.isrc[i] = d_in[18 + i];
  pa.idst[0] = c_seq; pa.idst[1] = c_lex; pa.idst[2] = c_pos_s; pa.idst[3] = c_pos_e;
  prep_k<<<dim3(64, 20), 256, 0, stream>>>(pa, d_in[1], flags);

  // 2) P tables (bf16, +bf in table 0) + q/k (bf16) + v (bf16, transposed)
  GArgs gA = {};
  for (int z = 0; z < 4; z++)
    gA.d[z] = {c_pe, c_Wf, (z == 0) ? c_bf : nullptr, Ptab_bf + (long)z * 513 * 512,
               513, 512, 512, 512, 2048, z * 512, 512, 1, 0, 0};
  gA.d[4] = {c_query, c_Wq, c_bq, q_n, 512, 512, 512, 512, 512, 0, 512, 1, 0, 0};
  gA.d[5] = {c_key,   c_Wk, c_bk, k_n, 512, 512, 512, 512, 512, 0, 512, 1, 0, 0};
  gA.d[6] = {c_value, c_Wv, c_bv, v_t, 512, 512, 512, 512, 512, 0, 512, 1, 1, 0};
  gemm2_k<<<dim3(8, 9, 7), 256, 0, stream>>>(gA, flags);

  // 3) qv/qu + cbv
  qvb3_k<<<1024, 256, 0, stream>>>(q_n, c_u, c_v, c_br, qv_n, qu_n, cbv_buf);

  // 4) wproj (bf16) + S_AC (f32), one dispatch
  GArgs gB = {};
  for (int z = 0; z < 16; z++) {
    const int b = z >> 3, h = z & 7;
    gB.d[z] = {qv_n + b * 131072 + h * 64, WrT, nullptr, wbuf_bf + (long)z * 131072,
               256, 512, 64, 512, 512, h * 64, 512, 1, 0, 0};
  }
  for (int z = 0; z < 16; z++) {
    const int b = z >> 3, h = z & 7;
    gB.d[16 + z] = {qu_n + b * 131072 + h * 64, k_n + b * 131072 + h * 64, nullptr,
                    S_AC + (long)z * 65536, 256, 256, 64, 512, 512, 0, 256, 0, 0, 0};
  }
  gemm2_k<<<dim3(8, 4, 32), 256, 0, stream>>>(gB, flags);

  // 5) scoring (relu-MFMA + AC + cbv) -> S_full
  score3_k<<<dim3(256, 2, 8), 128, 0, stream>>>(
      Ptab_bf, S_AC, cbv_buf, wbuf_bf, c_seq, c_lex, c_pos_s, c_pos_e, S_full);

  // 6) softmax -> attn_bf
  softmax_k<<<dim3(256, 2), 256, 0, stream>>>(S_full, c_seq, c_lex, attn_bf);

  // 7) attn @ V via MFMA -> out_pre_bf [b,i,h*64+d]
  GArgs gV = {};
  for (int z = 0; z < 16; z++) {
    const int b = z >> 3, h = z & 7;
    gV.d[z] = {attn_bf + (long)z * 65536, v_t + (long)(h * 64) * 512 + b * 256, nullptr,
               out_pre_bf + b * 131072 + h * 64, 256, 64, 256, 256, 512, 0, 512, 1, 0, 0};
  }
  gemm2_k<<<dim3(1, 4, 16), 256, 0, stream>>>(gV, flags);

  // 8) final: out = out_pre @ Wo.T + bo -> d_out (dtype per flag)
  GArgs gC = {};
  gC.d[0] = {out_pre_bf, c_Wo, c_bo, d_out, 512, 512, 512, 512, 512, 0, 512, 2, 0, 0};
  gemm2_k<<<dim3(8, 8, 1), 256, 0, stream>>>(gC, flags);
}